// Round 7
// baseline (376.347 us; speedup 1.0000x reference)
//
#include <hip/hip_runtime.h>
#include <math.h>

// ============================================================================
// TransformerEncoder_gram round 7:
//  - attn: T14 async-STAGE split (next K/V tile global->REG early, ds_write
//    after barrier) -> hides the vmcnt drain that 2-blocks/CU can't cover.
//  - attn: drop sN4 LDS stage (direct global f32x4 reads, L2-resident).
//  - proj_vg epilogue writes TRANSPOSED bf16 partials vT1/vT2 (kills the
//    64 MB fp32 vtrans round-trip); fused norms+vsum kernel.
//  - fused cast+splitW prep kernel.  8 -> 6 launches.
// ============================================================================

typedef short bf16x8 __attribute__((ext_vector_type(8)));
typedef float f32x4  __attribute__((ext_vector_type(4)));
typedef unsigned int u32x4 __attribute__((ext_vector_type(4)));
typedef unsigned short u16x4 __attribute__((ext_vector_type(4)));

#define MFMA16(a,b,c) __builtin_amdgcn_mfma_f32_16x16x32_bf16((a),(b),(c),0,0,0)

static constexpr float LOG2E_F = 1.4426950408889634f;
static constexpr float CBRT_L2E = 1.12994722f;     // log2e^(1/3)
static constexpr float DEFER_THR = 11.54156033f;   // 8 * log2e
static constexpr float EPS_SCALED = 2.0813689e-8f; // 1e-8 * log2e^2

typedef const __attribute__((address_space(1))) unsigned int gas_u32;
typedef __attribute__((address_space(3))) unsigned int las_u32;

__device__ __forceinline__ void gload16(const void* g, void* l){
  __builtin_amdgcn_global_load_lds((gas_u32*)g, (las_u32*)l, 16, 0, 0);
}

__device__ __forceinline__ float b2f(unsigned short s){
  union { unsigned u; float f; } v; v.u = ((unsigned)s) << 16; return v.f;
}
__device__ __forceinline__ unsigned short f2b(float f){
  union { float f; unsigned u; } v; v.f = f;
  unsigned r = v.u + 0x7fffu + ((v.u >> 16) & 1u);
  return (unsigned short)(r >> 16);
}

// ---------------------------------------------------------------------------
// prep: blocks 0..6143 cast X fp32->bf16; blocks 6144..8191 split W hi/lo.
// ---------------------------------------------------------------------------
__global__ __launch_bounds__(256) void prep_kernel(
    const float* __restrict__ xq, const float* __restrict__ x1,
    const float* __restrict__ x2,
    const float* w0, const float* w1, const float* w2, const float* w3,
    const float* w4, const float* w5, const float* w6, const float* w7,
    unsigned short* __restrict__ xhi,
    unsigned short* __restrict__ whi, unsigned short* __restrict__ wlo)
{
  const int blk = blockIdx.x, tid = threadIdx.x;
  const size_t NX = (size_t)8192*512, NW = (size_t)512*512;
  if (blk < 6144){
    const int y = blk >> 11;                 // 0..2
    const int i = ((blk & 2047)*256 + tid);  // x8 elems
    const float* src = (y == 0) ? xq : ((y == 1) ? x1 : x2);
    f32x4 v0 = *(const f32x4*)&src[(size_t)i*8];
    f32x4 v1 = *(const f32x4*)&src[(size_t)i*8 + 4];
    bf16x8 o;
    #pragma unroll
    for (int j = 0; j < 4; ++j){
      o[j]   = (short)f2b(v0[j]);
      o[j+4] = (short)f2b(v1[j]);
    }
    *(bf16x8*)&xhi[(size_t)y*NX + (size_t)i*8] = o;
  } else {
    const int y = (blk - 6144) >> 8;         // 0..7
    const int t = ((blk - 6144) & 255)*256 + tid;   // x4 elems
    const float* src = w0;
    if (y == 1) src = w1; if (y == 2) src = w2; if (y == 3) src = w3;
    if (y == 4) src = w4; if (y == 5) src = w5; if (y == 6) src = w6;
    if (y == 7) src = w7;
    f32x4 v = *(const f32x4*)&src[(size_t)t*4];
    u16x4 hh, ll_;
    #pragma unroll
    for (int j = 0; j < 4; ++j){
      unsigned short h = f2b(v[j]);
      hh[j] = h;
      ll_[j] = f2b(v[j] - b2f(h));
    }
    *(u16x4*)&whi[(size_t)y*NW + (size_t)t*4] = hh;
    *(u16x4*)&wlo[(size_t)y*NW + (size_t)t*4] = ll_;
  }
}

// ---------------------------------------------------------------------------
// q/k1/k2 projections: 128x128 tile, BK=32, dbuf gload_lds, 2-pass single acc.
// grid (64, 12): job = y>>2 in {0,1,2}, e0 = (y&3)*128.  LDS 48 KB, 3 blk/CU.
// ---------------------------------------------------------------------------
__global__ __launch_bounds__(256,3) void proj_qk_kernel(
    const unsigned short* __restrict__ xhi,
    const unsigned short* __restrict__ whi, const unsigned short* __restrict__ wlo,
    const float* __restrict__ bq, const float* __restrict__ bk1,
    const float* __restrict__ bk2,
    unsigned short* __restrict__ qh_hi, unsigned short* __restrict__ qh_lo,
    unsigned short* __restrict__ k1h_hi, unsigned short* __restrict__ k1h_lo,
    unsigned short* __restrict__ k2h_hi, unsigned short* __restrict__ k2h_lo)
{
  __shared__ unsigned short smem[2*3*4096];
  const int tid = threadIdx.x, w = tid >> 6, l = tid & 63;
  const int y = blockIdx.y, job = y >> 2;
  const int r0 = blockIdx.x * 128, e0 = (y & 3) * 128;
  const int lrow = l & 15, kg = l >> 4;

  const size_t NXs = (size_t)8192*512, NWs = (size_t)512*512;
  const unsigned short* Ahi = xhi + (size_t)job * NXs;
  const unsigned short* B1  = whi + (size_t)job * NWs;
  const unsigned short* B2  = wlo + (size_t)job * NWs;

  f32x4 acc[4][4];
  #pragma unroll
  for (int m = 0; m < 4; ++m)
    #pragma unroll
    for (int n = 0; n < 4; ++n) acc[m][n] = (f32x4){0.f,0.f,0.f,0.f};

  const int sgsw = ((l & 3) ^ ((l >> 3) & 3)) * 8;
  const int srA = r0 + w*16 + (l >> 2);
  const int srB = e0 + w*16 + (l >> 2);

  auto stage = [&](int buf, int kk){
    const int lb = buf*3*4096 + w*512;
    #pragma unroll
    for (int j = 0; j < 2; ++j){
      const size_t ga = (size_t)(srA + j*64)*512 + kk + sgsw;
      const size_t gb = (size_t)(srB + j*64)*512 + kk + sgsw;
      gload16(&Ahi[ga], &smem[lb + 0    + j*2048]);
      gload16(&B1[gb],  &smem[lb + 4096 + j*2048]);
      gload16(&B2[gb],  &smem[lb + 8192 + j*2048]);
    }
  };

  const int rowA = (w >> 1)*64 + lrow;
  const int rowB = (w & 1)*64 + lrow;
  const int kgs  = (kg ^ ((lrow >> 1) & 3)) * 8;

  auto compute = [&](int buf){
    const int bb = buf*3*4096;
    bf16x8 ah[4];
    #pragma unroll
    for (int m = 0; m < 4; ++m)
      ah[m] = *(const bf16x8*)&smem[bb + (rowA + m*16)*32 + kgs];
    #pragma unroll
    for (int n = 0; n < 4; ++n){
      const int rb = (rowB + n*16)*32 + kgs;
      bf16x8 b1 = *(const bf16x8*)&smem[bb + 4096 + rb];
      bf16x8 b2 = *(const bf16x8*)&smem[bb + 8192 + rb];
      #pragma unroll
      for (int m = 0; m < 4; ++m){
        acc[m][n] = MFMA16(ah[m], b1, acc[m][n]);
        acc[m][n] = MFMA16(ah[m], b2, acc[m][n]);
      }
    }
  };

  stage(0, 0);
  __syncthreads();
  for (int t = 0; t < 16; ++t){
    if (t < 15) stage((t+1) & 1, (t+1)*32);
    compute(t & 1);
    __syncthreads();
  }

  const float* bias = (job == 0) ? bq : ((job == 1) ? bk1 : bk2);
  const float scale = (job == 0) ? 0.125f*CBRT_L2E : CBRT_L2E;
  unsigned short* oH = (job == 0) ? qh_hi : ((job == 1) ? k1h_hi : k2h_hi);
  unsigned short* oL = (job == 0) ? qh_lo : ((job == 1) ? k1h_lo : k2h_lo);
  #pragma unroll
  for (int n = 0; n < 4; ++n){
    const int e = e0 + (w & 1)*64 + n*16 + lrow;
    const float bv = bias[e];
    #pragma unroll
    for (int m = 0; m < 4; ++m){
      #pragma unroll
      for (int q = 0; q < 4; ++q){
        const int r = r0 + (w >> 1)*64 + m*16 + kg*4 + q;
        const float yv = (acc[m][n][q] + bv) * scale;
        const int bh = ((r & 7) << 3) + (e >> 6);
        const size_t off = ((size_t)bh*1024 + (r >> 3))*64 + (e & 63);
        unsigned short hh = f2b(yv);
        oH[off] = hh;
        oL[off] = f2b(yv - b2f(hh));
      }
    }
  }
}

// ---------------------------------------------------------------------------
// gated-v projections: v 1-pass + gate 1-pass (dual acc); epilogue writes
// TRANSPOSED bf16 partial vT_m[bh][d][t] directly (no fp32 round-trip).
// grid (64, 8): job = 3 + (y>>2), e0 = (y&3)*128.  LDS 48 KB.
// ---------------------------------------------------------------------------
__global__ __launch_bounds__(256,2) void proj_vg_kernel(
    const unsigned short* __restrict__ xhi,
    const unsigned short* __restrict__ whi,
    const float* __restrict__ bv1, const float* __restrict__ bg1,
    const float* __restrict__ bv2, const float* __restrict__ bg2,
    unsigned short* __restrict__ vT1, unsigned short* __restrict__ vT2)
{
  __shared__ unsigned short smem[2*3*4096];
  const int tid = threadIdx.x, w = tid >> 6, l = tid & 63;
  const int y = blockIdx.y, job = 3 + (y >> 2);
  const int r0 = blockIdx.x * 128, e0 = (y & 3) * 128;
  const int lrow = l & 15, kg = l >> 4;

  const size_t NXs = (size_t)8192*512, NWs = (size_t)512*512;
  const unsigned short* Ahi = xhi + (size_t)(job - 2) * NXs;     // x1 or x2
  const unsigned short* B1  = whi + (size_t)((job == 3) ? 3 : 4) * NWs; // Wv
  const unsigned short* B2  = whi + (size_t)((job == 3) ? 5 : 6) * NWs; // Wg

  f32x4 acc[4][4], acc2[4][4];
  #pragma unroll
  for (int m = 0; m < 4; ++m)
    #pragma unroll
    for (int n = 0; n < 4; ++n){
      acc[m][n] = (f32x4){0.f,0.f,0.f,0.f};
      acc2[m][n] = (f32x4){0.f,0.f,0.f,0.f};
    }

  const int sgsw = ((l & 3) ^ ((l >> 3) & 3)) * 8;
  const int srA = r0 + w*16 + (l >> 2);
  const int srB = e0 + w*16 + (l >> 2);

  auto stage = [&](int buf, int kk){
    const int lb = buf*3*4096 + w*512;
    #pragma unroll
    for (int j = 0; j < 2; ++j){
      const size_t ga = (size_t)(srA + j*64)*512 + kk + sgsw;
      const size_t gb = (size_t)(srB + j*64)*512 + kk + sgsw;
      gload16(&Ahi[ga], &smem[lb + 0    + j*2048]);
      gload16(&B1[gb],  &smem[lb + 4096 + j*2048]);
      gload16(&B2[gb],  &smem[lb + 8192 + j*2048]);
    }
  };

  const int rowA = (w >> 1)*64 + lrow;
  const int rowB = (w & 1)*64 + lrow;
  const int kgs  = (kg ^ ((lrow >> 1) & 3)) * 8;

  auto compute = [&](int buf){
    const int bb = buf*3*4096;
    bf16x8 ah[4];
    #pragma unroll
    for (int m = 0; m < 4; ++m)
      ah[m] = *(const bf16x8*)&smem[bb + (rowA + m*16)*32 + kgs];
    #pragma unroll
    for (int n = 0; n < 4; ++n){
      const int rb = (rowB + n*16)*32 + kgs;
      bf16x8 b1 = *(const bf16x8*)&smem[bb + 4096 + rb];
      bf16x8 b2 = *(const bf16x8*)&smem[bb + 8192 + rb];
      #pragma unroll
      for (int m = 0; m < 4; ++m){
        acc[m][n]  = MFMA16(ah[m], b1, acc[m][n]);
        acc2[m][n] = MFMA16(ah[m], b2, acc2[m][n]);
      }
    }
  };

  stage(0, 0);
  __syncthreads();
  for (int t = 0; t < 16; ++t){
    if (t < 15) stage((t+1) & 1, (t+1)*32);
    compute(t & 1);
    __syncthreads();
  }

  const float* bvv = (job == 3) ? bv1 : bv2;
  const float* bgg = (job == 3) ? bg1 : bg2;
  unsigned short* vTp = (job == 3) ? vT1 : vT2;
  #pragma unroll
  for (int n = 0; n < 4; ++n){
    const int e = e0 + (w & 1)*64 + n*16 + lrow;
    const float bv = bvv[e], bg_ = bgg[e];
    const int h_ = e >> 6, d_ = e & 63;
    #pragma unroll
    for (int m = 0; m < 4; ++m){
      #pragma unroll
      for (int q = 0; q < 4; ++q){
        const int r = r0 + (w >> 1)*64 + m*16 + kg*4 + q;
        const float yv = acc[m][n][q] + bv;
        const float yg = acc2[m][n][q] + bg_;
        const float sg = 1.0f / (1.0f + exp2f(-yg * LOG2E_F));
        const int b_ = r & 7, t_ = r >> 3;
        vTp[((size_t)((b_ << 3) + h_)*64 + d_)*1024 + t_] = f2b(yv * sg);
      }
    }
  }
}

// ---------------------------------------------------------------------------
// Out projection: 64x128 tile (512 blocks), 2-pass.
// ---------------------------------------------------------------------------
__global__ __launch_bounds__(256,2) void gemmout_kernel(
    const unsigned short* __restrict__ Ahi,
    const unsigned short* __restrict__ Bhi, const unsigned short* __restrict__ Blo,
    const float* __restrict__ bias, float* __restrict__ outF)
{
  __shared__ unsigned short smem[2*10240];
  const int tid = threadIdx.x, w = tid >> 6, l = tid & 63;
  const int r0 = blockIdx.x * 64, e0 = blockIdx.y * 128;
  const int lrow = l & 15, kg = l >> 4;

  f32x4 acc[2][4];
  #pragma unroll
  for (int m = 0; m < 2; ++m)
    #pragma unroll
    for (int n = 0; n < 4; ++n) acc[m][n] = (f32x4){0.f,0.f,0.f,0.f};

  const int sgsw = ((l & 3) ^ ((l >> 3) & 3)) * 8;
  const int srA = r0 + w*16 + (l >> 2);
  const int srB = e0 + w*16 + (l >> 2);

  auto stage = [&](int buf, int kk){
    const int lb = buf*10240;
    gload16(&Ahi[(size_t)srA*512 + kk + sgsw], &smem[lb + tid*8]);
    #pragma unroll
    for (int j = 0; j < 2; ++j){
      const size_t gb = (size_t)(srB + j*64)*512 + kk + sgsw;
      gload16(&Bhi[gb], &smem[lb + 2048 + (tid + j*256)*8]);
      gload16(&Blo[gb], &smem[lb + 6144 + (tid + j*256)*8]);
    }
  };

  const int rowA = (w >> 1)*32 + lrow;
  const int rowB = (w & 1)*64 + lrow;
  const int kgs  = (kg ^ ((lrow >> 1) & 3)) * 8;

  auto compute = [&](int buf){
    const int bb = buf*10240;
    bf16x8 ah[2];
    #pragma unroll
    for (int m = 0; m < 2; ++m)
      ah[m] = *(const bf16x8*)&smem[bb + (rowA + m*16)*32 + kgs];
    #pragma unroll
    for (int n = 0; n < 4; ++n){
      const int rb = (rowB + n*16)*32 + kgs;
      bf16x8 bh = *(const bf16x8*)&smem[bb + 2048 + rb];
      bf16x8 bl = *(const bf16x8*)&smem[bb + 6144 + rb];
      #pragma unroll
      for (int m = 0; m < 2; ++m){
        acc[m][n] = MFMA16(ah[m], bh, acc[m][n]);
        acc[m][n] = MFMA16(ah[m], bl, acc[m][n]);
      }
    }
  };

  stage(0, 0);
  __syncthreads();
  for (int t = 0; t < 16; ++t){
    if (t < 15) stage((t+1) & 1, (t+1)*32);
    compute(t & 1);
    __syncthreads();
  }

  #pragma unroll
  for (int n = 0; n < 4; ++n){
    const int e = e0 + (w & 1)*64 + n*16 + lrow;
    const float bv = bias[e];
    #pragma unroll
    for (int m = 0; m < 2; ++m){
      #pragma unroll
      for (int q = 0; q < 4; ++q){
        const int r = r0 + (w >> 1)*32 + m*16 + kg*4 + q;
        outF[(size_t)r*512 + e] = acc[m][n][q] + bv;
      }
    }
  }
}

// ---------------------------------------------------------------------------
// post: blocks 0..255 = gram scalars; blocks 256..2303 = vT = vT1 + vT2.
// ---------------------------------------------------------------------------
__global__ __launch_bounds__(256) void post_kernel(
    const unsigned short* __restrict__ qh, const unsigned short* __restrict__ ql,
    const unsigned short* __restrict__ k1h, const unsigned short* __restrict__ k1l,
    const unsigned short* __restrict__ k2h, const unsigned short* __restrict__ k2l,
    float* __restrict__ ll, f32x4* __restrict__ nrm4,
    const unsigned short* __restrict__ vT1, const unsigned short* __restrict__ vT2,
    unsigned short* __restrict__ vT)
{
  const int blk = blockIdx.x, tid = threadIdx.x;
  if (blk < 256){
    const int idx = blk*256 + tid;
    const size_t base = (size_t)idx * 64;
    float sll = 0.f, svv = 0.f, saa = 0.f, sva = 0.f;
    #pragma unroll
    for (int j = 0; j < 8; ++j){
      bf16x8 q_h = *(const bf16x8*)&qh[base + j*8];
      bf16x8 q_l = *(const bf16x8*)&ql[base + j*8];
      bf16x8 a_h = *(const bf16x8*)&k1h[base + j*8];
      bf16x8 a_l = *(const bf16x8*)&k1l[base + j*8];
      bf16x8 c_h = *(const bf16x8*)&k2h[base + j*8];
      bf16x8 c_l = *(const bf16x8*)&k2l[base + j*8];
      #pragma unroll
      for (int i = 0; i < 8; ++i){
        float qv = b2f((unsigned short)q_h[i]) + b2f((unsigned short)q_l[i]);
        float a1 = b2f((unsigned short)a_h[i]) + b2f((unsigned short)a_l[i]);
        float a2 = b2f((unsigned short)c_h[i]) + b2f((unsigned short)c_l[i]);
        sll += qv*qv; svv += a1*a1; saa += a2*a2; sva += a1*a2;
      }
    }
    ll[idx] = sll;
    nrm4[idx] = (f32x4){svv*saa - sva*sva, saa, 2.0f*sva, svv};
  } else {
    const size_t i = ((size_t)(blk - 256)*256 + tid) * 8;
    bf16x8 a = *(const bf16x8*)&vT1[i];
    bf16x8 b = *(const bf16x8*)&vT2[i];
    bf16x8 o;
    #pragma unroll
    for (int j = 0; j < 8; ++j)
      o[j] = (short)f2b(b2f((unsigned short)a[j]) + b2f((unsigned short)b[j]));
    *(bf16x8*)&vT[i] = o;
  }
}

// ---------------------------------------------------------------------------
// Fused gram-det attention. QBLK=128 (4 waves x 32 rows), KVBLK=64.
// T14 async-stage: next tile global->regs early, ds_write after barrier.
// 1-D grid 512, XCD-swizzled: bh = blk & 63.
// ---------------------------------------------------------------------------
__global__ __launch_bounds__(256,2) void attn_kernel(
    const unsigned short* __restrict__ qhh, const unsigned short* __restrict__ qhl,
    const unsigned short* __restrict__ k1hh, const unsigned short* __restrict__ k1hl,
    const unsigned short* __restrict__ k2hh, const unsigned short* __restrict__ k2hl,
    const unsigned short* __restrict__ vTh,
    const float* __restrict__ llv, const f32x4* __restrict__ nrm4,
    unsigned short* __restrict__ aoHi)
{
  __shared__ unsigned short sK1h[4096];
  __shared__ unsigned short sK1l[4096];
  __shared__ unsigned short sK2h[4096];
  __shared__ unsigned short sK2l[4096];
  __shared__ unsigned short sVh[4096];
  __shared__ unsigned short sPh[8192];

  const int bh = blockIdx.x & 63, l0 = (blockIdx.x >> 6) * 128;
  const int tid = threadIdx.x, w = tid >> 6, lane = tid & 63;
  const int lrow = lane & 15, kg = lane >> 4;

  bf16x8 qfh[2][2], qfl[2][2];
  #pragma unroll
  for (int m = 0; m < 2; ++m){
    const size_t qb = ((size_t)bh*1024 + l0 + w*32 + m*16 + lrow)*64 + kg*8;
    qfh[m][0] = *(const bf16x8*)&qhh[qb];
    qfl[m][0] = *(const bf16x8*)&qhl[qb];
    qfh[m][1] = *(const bf16x8*)&qhh[qb + 32];
    qfl[m][1] = *(const bf16x8*)&qhl[qb + 32];
  }
  float ll_r[2][4];
  #pragma unroll
  for (int m = 0; m < 2; ++m)
    #pragma unroll
    for (int q = 0; q < 4; ++q)
      ll_r[m][q] = llv[bh*1024 + l0 + w*32 + m*16 + kg*4 + q];

  f32x4 accO[2][4];
  #pragma unroll
  for (int m = 0; m < 2; ++m)
    #pragma unroll
    for (int i = 0; i < 4; ++i) accO[m][i] = (f32x4){0.f,0.f,0.f,0.f};
  float mn[2][4], s_run[2][4];
  #pragma unroll
  for (int m = 0; m < 2; ++m)
    #pragma unroll
    for (int q = 0; q < 4; ++q){ mn[m][q] = 1e30f; s_run[m][q] = 0.f; }

  // staging geometry: granule c -> LDS c*16B (linear), source granule swizzled
  const int c0 = tid, c1 = tid + 256;
  const int r0g = c0 >> 3, g0 = ((c0 & 7) ^ (r0g & 7)) * 8;
  const int r1g = c1 >> 3, g1 = ((c1 & 7) ^ (r1g & 7)) * 8;

  u32x4 st0,st1,st2,st3,st4,st5,st6,st7,st8,st9;     // T14 reg-stage buffer
  auto LOADREGS = [&](int ss2){
    const size_t kb = (size_t)bh*1024 + ss2;
    const size_t k0 = (kb + r0g)*64 + g0;
    const size_t k1_ = (kb + r1g)*64 + g1;
    st0 = *(const u32x4*)&k1hh[k0];  st1 = *(const u32x4*)&k1hh[k1_];
    st2 = *(const u32x4*)&k1hl[k0];  st3 = *(const u32x4*)&k1hl[k1_];
    st4 = *(const u32x4*)&k2hh[k0];  st5 = *(const u32x4*)&k2hh[k1_];
    st6 = *(const u32x4*)&k2hl[k0];  st7 = *(const u32x4*)&k2hl[k1_];
    const size_t v0 = ((size_t)bh*64 + r0g)*1024 + ss2 + g0;
    const size_t v1 = ((size_t)bh*64 + r1g)*1024 + ss2 + g1;
    st8 = *(const u32x4*)&vTh[v0];   st9 = *(const u32x4*)&vTh[v1];
  };
  auto WRITELDS = [&](){
    *(u32x4*)&sK1h[c0*8] = st0;  *(u32x4*)&sK1h[c1*8] = st1;
    *(u32x4*)&sK1l[c0*8] = st2;  *(u32x4*)&sK1l[c1*8] = st3;
    *(u32x4*)&sK2h[c0*8] = st4;  *(u32x4*)&sK2h[c1*8] = st5;
    *(u32x4*)&sK2l[c0*8] = st6;  *(u32x4*)&sK2l[c1*8] = st7;
    *(u32x4*)&sVh[c0*8]  = st8;  *(u32x4*)&sVh[c1*8]  = st9;
  };

  LOADREGS(0);
  WRITELDS();
  __syncthreads();

  for (int ss = 0; ss < 1024; ss += 64){
    if (ss + 64 < 1024) LOADREGS(ss + 64);   // issue early; hides under compute

    float p_[2][4][4];
    float tmn[2][4];
    #pragma unroll
    for (int m = 0; m < 2; ++m)
      #pragma unroll
      for (int q = 0; q < 4; ++q) tmn[m][q] = 1e30f;

    #pragma unroll
    for (int nt = 0; nt < 4; ++nt){
      f32x4 lv[2], la[2];
      #pragma unroll
      for (int m = 0; m < 2; ++m){ lv[m] = (f32x4){0.f,0.f,0.f,0.f}; la[m] = (f32x4){0.f,0.f,0.f,0.f}; }
      __builtin_amdgcn_s_setprio(1);
      #pragma unroll
      for (int ks = 0; ks < 2; ++ks){
        const int row = nt*16 + lrow;
        const int off = row*64 + (((ks*4 + kg) ^ (row & 7)) * 8);
        bf16x8 b1h = *(const bf16x8*)&sK1h[off];
        bf16x8 b1l = *(const bf16x8*)&sK1l[off];
        bf16x8 b2h = *(const bf16x8*)&sK2h[off];
        bf16x8 b2l = *(const bf16x8*)&sK2l[off];
        #pragma unroll
        for (int m = 0; m < 2; ++m){
          lv[m] = MFMA16(qfh[m][ks], b1h, lv[m]);
          lv[m] = MFMA16(qfh[m][ks], b1l, lv[m]);
          lv[m] = MFMA16(qfl[m][ks], b1h, lv[m]);
          la[m] = MFMA16(qfh[m][ks], b2h, la[m]);
          la[m] = MFMA16(qfh[m][ks], b2l, la[m]);
          la[m] = MFMA16(qfl[m][ks], b2h, la[m]);
        }
      }
      __builtin_amdgcn_s_setprio(0);
      f32x4 n4 = *(const f32x4*)&nrm4[(size_t)bh*1024 + ss + nt*16 + lrow];
      const float cross = n4[0], c_aa = n4[1], c_va2 = n4[2], c_vv = n4[3];
      #pragma unroll
      for (int m = 0; m < 2; ++m){
        #pragma unroll
        for (int q = 0; q < 4; ++q){
          const float flv = lv[m][q], fla = la[m][q];
          float t = fmaf(-c_vv, fla*fla, (flv*fla)*c_va2);
          t = fmaf(-c_aa, flv*flv, t);
          const float det = fmaf(ll_r[m][q], cross, t);
          const float sq = __builtin_amdgcn_sqrtf(fmaxf(det, EPS_SCALED));
          p_[m][nt][q] = sq;
          tmn[m][q] = fminf(tmn[m][q], sq);
        }
      }
    }
    #pragma unroll
    for (int m = 0; m < 2; ++m)
      #pragma unroll
      for (int q = 0; q < 4; ++q){
        tmn[m][q] = fminf(tmn[m][q], __shfl_xor(tmn[m][q], 1));
        tmn[m][q] = fminf(tmn[m][q], __shfl_xor(tmn[m][q], 2));
        tmn[m][q] = fminf(tmn[m][q], __shfl_xor(tmn[m][q], 4));
        tmn[m][q] = fminf(tmn[m][q], __shfl_xor(tmn[m][q], 8));
      }
    int up = 0;
    #pragma unroll
    for (int m = 0; m < 2; ++m)
      #pragma unroll
      for (int q = 0; q < 4; ++q) up |= (tmn[m][q] < mn[m][q] - DEFER_THR) ? 1 : 0;
    if (__any(up)){
      #pragma unroll
      for (int m = 0; m < 2; ++m)
        #pragma unroll
        for (int q = 0; q < 4; ++q){
          const float mnn = fminf(mn[m][q], tmn[m][q]);
          const float rs = __builtin_amdgcn_exp2f(mnn - mn[m][q]);
          mn[m][q] = mnn;
          s_run[m][q] *= rs;
          #pragma unroll
          for (int dt = 0; dt < 4; ++dt) accO[m][dt][q] *= rs;
        }
    }
    float ps[2][4];
    #pragma unroll
    for (int m = 0; m < 2; ++m)
      #pragma unroll
      for (int q = 0; q < 4; ++q) ps[m][q] = 0.f;
    #pragma unroll
    for (int nt = 0; nt < 4; ++nt)
      #pragma unroll
      for (int m = 0; m < 2; ++m)
        #pragma unroll
        for (int q = 0; q < 4; ++q){
          const float e = __builtin_amdgcn_exp2f(mn[m][q] - p_[m][nt][q]);
          p_[m][nt][q] = e;
          ps[m][q] += e;
        }
    #pragma unroll
    for (int m = 0; m < 2; ++m)
      #pragma unroll
      for (int q = 0; q < 4; ++q){
        float v = ps[m][q];
        v += __shfl_xor(v, 1); v += __shfl_xor(v, 2);
        v += __shfl_xor(v, 4); v += __shfl_xor(v, 8);
        s_run[m][q] += v;
      }

    #pragma unroll
    for (int m = 0; m < 2; ++m){
      #pragma unroll
      for (int nt = 0; nt < 4; ++nt){
        const int col = nt*16 + lrow;
        const int cg = col >> 3, cr = col & 7;
        #pragma unroll
        for (int qp = 0; qp < 2; ++qp){
          unsigned int pk;
          asm("v_cvt_pk_bf16_f32 %0, %1, %2" : "=v"(pk)
              : "v"(p_[m][nt][qp*2]), "v"(p_[m][nt][qp*2+1]));
          const int ra = m*16 + kg*4 + qp*2, rb = ra + 1;
          sPh[w*2048 + ra*64 + ((cg ^ (ra & 7))*8) + cr] = (unsigned short)(pk & 0xffffu);
          sPh[w*2048 + rb*64 + ((cg ^ (rb & 7))*8) + cr] = (unsigned short)(pk >> 16);
        }
      }
    }

    __builtin_amdgcn_s_setprio(1);
    #pragma unroll
    for (int ks = 0; ks < 2; ++ks){
      bf16x8 pa[2];
      #pragma unroll
      for (int m = 0; m < 2; ++m){
        const int prow = m*16 + lrow;
        pa[m] = *(const bf16x8*)&sPh[w*2048 + prow*64 + (((ks*4 + kg) ^ (prow & 7))*8)];
      }
      #pragma unroll
      for (int dt = 0; dt < 4; ++dt){
        const int vrow = dt*16 + lrow;
        bf16x8 bvh = *(const bf16x8*)&sVh[vrow*64 + (((ks*4 + kg) ^ (vrow & 7))*8)];
        #pragma unroll
        for (int m = 0; m < 2; ++m)
          accO[m][dt] = MFMA16(pa[m], bvh, accO[m][dt]);
      }
    }
    __builtin_amdgcn_s_setprio(0);

    __syncthreads();                 // all waves done reading this tile's LDS
    if (ss + 64 < 1024){
      WRITELDS();                    // waitcnt(vmcnt) here — loads long done
      __syncthreads();               // next tile ready
    }
  }

  const int b = bh >> 3, h = bh & 7;
  #pragma unroll
  for (int m = 0; m < 2; ++m){
    float rcp[4];
    #pragma unroll
    for (int q = 0; q < 4; ++q) rcp[q] = __builtin_amdgcn_rcpf(s_run[m][q]);
    #pragma unroll
    for (int dt = 0; dt < 4; ++dt){
      const int d = dt*16 + lrow;
      #pragma unroll
      for (int q = 0; q < 4; ++q){
        const int l_ = l0 + w*32 + m*16 + kg*4 + q;
        aoHi[((size_t)l_*8 + b)*512 + h*64 + d] = f2b(accO[m][dt][q] * rcp[q]);
      }
    }
  }
}

// ===========================================================================
extern "C" void kernel_launch(void* const* d_in, const int* in_sizes, int n_in,
                              void* d_out, int out_size, void* d_ws, size_t ws_size,
                              hipStream_t stream)
{
  const float* query = (const float*)d_in[0];
  const float* mod1  = (const float*)d_in[1];
  const float* mod2  = (const float*)d_in[2];
  const float* bq  = (const float*)d_in[4];
  const float* bk1 = (const float*)d_in[6];
  const float* bk2 = (const float*)d_in[8];
  const float* bv1 = (const float*)d_in[10];
  const float* bv2 = (const float*)d_in[12];
  const float* bg1 = (const float*)d_in[14];
  const float* bg2 = (const float*)d_in[16];
  const float* bo  = (const float*)d_in[18];

  char* p = (char*)d_ws;
  auto take = [&](size_t bytes) -> char* {
    char* r = p; p += (bytes + 255) & ~(size_t)255; return r;
  };
  const size_t NX = (size_t)8192*512;
  const size_t NW = (size_t)512*512;
  const size_t XB = NX*2, WB = NW*2;
  const size_t HB = (size_t)64*1024*64*2;
  const size_t NB = (size_t)64*1024*4;

  unsigned short* xhi = (unsigned short*)take(3*XB);
  unsigned short* whi = (unsigned short*)take(8*WB);
  unsigned short* wlo = (unsigned short*)take(8*WB);
  unsigned short* qh_hi  = (unsigned short*)take(HB);
  unsigned short* qh_lo  = (unsigned short*)take(HB);
  unsigned short* k1h_hi = (unsigned short*)take(HB);
  unsigned short* k1h_lo = (unsigned short*)take(HB);
  unsigned short* k2h_hi = (unsigned short*)take(HB);
  unsigned short* k2h_lo = (unsigned short*)take(HB);
  unsigned short* vT1 = (unsigned short*)take(HB);
  unsigned short* vT2 = (unsigned short*)take(HB);
  unsigned short* vT  = (unsigned short*)take(HB);
  unsigned short* ao_hi = (unsigned short*)take(HB);
  float* llv = (float*)take(NB);
  f32x4* nrm4 = (f32x4*)take(4*NB);

  // ---- 1. fused cast + weight split ----
  prep_kernel<<<8192, 256, 0, stream>>>(
      query, mod1, mod2,
      (const float*)d_in[3], (const float*)d_in[5], (const float*)d_in[7],
      (const float*)d_in[9], (const float*)d_in[11], (const float*)d_in[13],
      (const float*)d_in[15], (const float*)d_in[17], xhi, whi, wlo);

  // ---- 2. projections ----
  proj_qk_kernel<<<dim3(64, 12), 256, 0, stream>>>(
      xhi, whi, wlo, bq, bk1, bk2,
      qh_hi, qh_lo, k1h_hi, k1h_lo, k2h_hi, k2h_lo);
  proj_vg_kernel<<<dim3(64, 8), 256, 0, stream>>>(
      xhi, whi, bv1, bg1, bv2, bg2, vT1, vT2);

  // ---- 3. fused gram scalars + V-sum ----
  post_kernel<<<2304, 256, 0, stream>>>(
      qh_hi, qh_lo, k1h_hi, k1h_lo, k2h_hi, k2h_lo,
      llv, nrm4, vT1, vT2, vT);

  // ---- 4. fused gram-det attention (T14 reg-staged) ----
  attn_kernel<<<512, 256, 0, stream>>>(
      qh_hi, qh_lo, k1h_hi, k1h_lo, k2h_hi, k2h_lo, vT,
      llv, nrm4, ao_hi);

  // ---- 5. output projection -> d_out ----
  gemmout_kernel<<<dim3(128, 4), 256, 0, stream>>>(
      ao_hi, whi + 7*NW, wlo + 7*NW, bo, (float*)d_out);
}